// Round 2
// baseline (78599.109 us; speedup 1.0000x reference)
//
#include <hip/hip_runtime.h>
#include <math.h>

#define TSTEPS 1024
#define HID    2048
#define IN_D   128
#define OUT_D  128
#define NWG    256
#define NTHR   512

#define LOG2PI_F 1.8378770664093453f

static __device__ __forceinline__ float sigmoidf_(float x) {
    return 1.0f / (1.0f + expf(-x));
}

// ---------------------------------------------------------------------------
// Persistent LSTM rollout kernel.
// Grid: 256 WGs x 512 threads. WG w owns h-indices [8w, 8w+8) and the 32 gate
// rows {g*2048 + 8w + i : g in 0..3, i in 0..7}. W_hh is register-resident:
// thread (rg=tid>>6, lane=tid&63) holds rows li=rg*4+m (m=0..3), k-slice
// [32*lane, 32*lane+32) -> 128 f32 in VGPRs. h propagates through a global
// double buffer with a monotonic-counter grid barrier each step.
// ---------------------------------------------------------------------------
__global__ __launch_bounds__(NTHR, 2)
void lstm_persist(const float* __restrict__ s0,
                  const float* __restrict__ Wih,
                  const float* __restrict__ Whh,
                  const float* __restrict__ bih,
                  const float* __restrict__ bhh,
                  float* __restrict__ hs_out,
                  unsigned int* __restrict__ ctr,
                  float* __restrict__ hbuf0,
                  float* __restrict__ hbuf1)
{
    __shared__ __align__(16) float ldsH[HID];          // staged h (swizzled)
    __shared__ __align__(16) float ldsWih[32 * IN_D];  // W_ih slice
    __shared__ __align__(16) float ldsX[2][IN_D];      // x double buffer
    __shared__ __align__(16) float partial[8][32];     // [octet][li]
    __shared__ __align__(16) float partial2[16][32];   // [seg][li] (ih dot)
    __shared__ float gsum[32];
    __shared__ float biasLds[32];

    const int tid   = threadIdx.x;
    const int wg    = blockIdx.x;
    const int hbase = wg * 8;
    const int rg    = tid >> 6;   // wave id 0..7
    const int lane  = tid & 63;

    // ---- init: W_ih slice + bias + x0 into LDS ----
    {
        const int row = tid >> 4;           // 0..31 (local gate row li)
        const int seg = tid & 15;           // 8 floats each
        const int grow = (row >> 3) * HID + hbase + (row & 7);
        const float4* src = (const float4*)(Wih + (size_t)grow * IN_D + seg * 8);
        float4 a = src[0], b = src[1];
        float4* dst = (float4*)(&ldsWih[row * IN_D + seg * 8]);
        dst[0] = a; dst[1] = b;
    }
    if (tid < 32) {
        const int grow = (tid >> 3) * HID + hbase + (tid & 7);
        biasLds[tid] = bih[grow] + bhh[grow];
        float4 x = ((const float4*)s0)[tid];
        ((float4*)&ldsX[0][0])[tid] = x;
    }

    // ---- W_hh -> registers (f32, full precision) ----
    float w[4][32];
#pragma unroll
    for (int m = 0; m < 4; ++m) {
        const int li = rg * 4 + m;
        const int grow = (li >> 3) * HID + hbase + (li & 7);
        const float4* src = (const float4*)(Whh + (size_t)grow * HID + lane * 32);
#pragma unroll
        for (int q = 0; q < 8; ++q) {
            float4 v = src[q];
            w[m][4*q+0] = v.x; w[m][4*q+1] = v.y;
            w[m][4*q+2] = v.z; w[m][4*q+3] = v.w;
        }
    }

    float c_reg = 0.0f;
    __syncthreads();

    for (int t = 0; t < TSTEPS; ++t) {
        const int cur = t & 1;
        const float* hb_cur = cur ? hbuf1 : hbuf0;
        float*       hb_nxt = cur ? hbuf0 : hbuf1;

        // ---- stage h into LDS, XOR-swizzled (16B chunk p = c ^ ((c>>3)&7)) ----
        {
            float4 hv = ((const float4*)hb_cur)[tid];
            const int p = tid ^ ((tid >> 3) & 7);
            ((float4*)ldsH)[p] = hv;
        }
        // prefetch next x (load early, LDS-write later)
        float4 xpre;
        const bool do_pre = (tid < 32) && (t + 1 < TSTEPS);
        if (do_pre) xpre = ((const float4*)(s0 + (size_t)(t + 1) * IN_D))[tid];
        __syncthreads();

        // ---- main recurrent matvec: 4 rows x 32 k per thread ----
        float acc[4] = {0.f, 0.f, 0.f, 0.f};
#pragma unroll
        for (int j = 0; j < 8; ++j) {
            const int c = 8 * lane + j;
            const int p = c ^ (lane & 7);
            float4 hv = ((const float4*)ldsH)[p];
#pragma unroll
            for (int m = 0; m < 4; ++m) {
                acc[m] += hv.x * w[m][4*j+0];
                acc[m] += hv.y * w[m][4*j+1];
                acc[m] += hv.z * w[m][4*j+2];
                acc[m] += hv.w * w[m][4*j+3];
            }
        }

        // ---- input-to-hidden partial (W_ih @ x_t), spread over all threads ----
        {
            const int row = tid >> 4;
            const int seg = tid & 15;
            const float* xv = &ldsX[cur][seg * 8];
            const float* wv = &ldsWih[row * IN_D + seg * 8];
            float p2 = 0.f;
#pragma unroll
            for (int q = 0; q < 8; ++q) p2 += xv[q] * wv[q];
            partial2[seg][row] = p2;
        }

        // ---- reduce main dot over k within wave (octets of 8 lanes) ----
#pragma unroll
        for (int m = 0; m < 4; ++m) {
            acc[m] += __shfl_xor(acc[m], 1);
            acc[m] += __shfl_xor(acc[m], 2);
            acc[m] += __shfl_xor(acc[m], 4);
        }
        if ((lane & 7) == 0) {
            float4 pv = make_float4(acc[0], acc[1], acc[2], acc[3]);
            *(float4*)&partial[lane >> 3][rg * 4] = pv;
        }
        if (do_pre) ((float4*)&ldsX[cur ^ 1][0])[tid] = xpre;
        __syncthreads();

        // ---- stage 2: final gate sums ----
        if (tid < 32) {
            float g = biasLds[tid];
#pragma unroll
            for (int o = 0; o < 8; ++o) g += partial[o][tid];
#pragma unroll
            for (int sgi = 0; sgi < 16; ++sgi) g += partial2[sgi][tid];
            gsum[tid] = g;
        }
        __syncthreads();

        // ---- cell update (threads 0..7 own one h-index each) ----
        if (tid < 8) {
            const float zi = gsum[tid];
            const float zf = gsum[8 + tid];
            const float zg = gsum[16 + tid];
            const float zo = gsum[24 + tid];
            const float ig = sigmoidf_(zi);
            const float fg = sigmoidf_(zf);
            const float og = sigmoidf_(zo);
            const float gg = tanhf(zg);
            c_reg = fg * c_reg + ig * gg;
            const float h = og * tanhf(c_reg);
            hb_nxt[hbase + tid] = h;
            hs_out[(size_t)t * HID + hbase + tid] = h;
        }

        // ---- grid barrier: release h writes, arrive, spin, acquire ----
        __threadfence();
        __syncthreads();
        if (tid == 0) {
            __hip_atomic_fetch_add(ctr, 1u, __ATOMIC_ACQ_REL, __HIP_MEMORY_SCOPE_AGENT);
            const unsigned int target = (unsigned int)(NWG * (t + 1));
            while (__hip_atomic_load(ctr, __ATOMIC_ACQUIRE, __HIP_MEMORY_SCOPE_AGENT) < target)
                __builtin_amdgcn_s_sleep(1);
        }
        __syncthreads();
        __threadfence();   // acquire: make other WGs' h writes visible to all lanes
    }
}

// ---------------------------------------------------------------------------
// Output head: mu/logvar GEMV + sample + logprob. Block = 4 timesteps,
// thread tid<128 -> mu row tid, tid>=128 -> lv row tid-128. hs is L2/L3-hot.
// ---------------------------------------------------------------------------
__global__ __launch_bounds__(256)
void out_head(const float* __restrict__ eps,
              const float* __restrict__ Wmu,
              const float* __restrict__ bmu,
              const float* __restrict__ Wlv,
              const float* __restrict__ blv,
              const float* __restrict__ hs,
              float* __restrict__ xs,
              float* __restrict__ lp)
{
    __shared__ __align__(16) float hlds[4][HID];
    __shared__ __align__(16) float exch[4][256];

    const int tid = threadIdx.x;
    const int t0  = blockIdx.x * 4;

    {
        const float4* src = (const float4*)(hs + (size_t)t0 * HID);
        float4* dst = (float4*)&hlds[0][0];
#pragma unroll
        for (int i = 0; i < 8; ++i)
            dst[tid + i * 256] = src[tid + i * 256];
    }
    __syncthreads();

    const int  jrow  = tid & 127;
    const bool is_lv = tid >= 128;
    const float* Wrow = (is_lv ? Wlv : Wmu) + (size_t)jrow * HID;
    const float  bias = is_lv ? blv[jrow] : bmu[jrow];

    float acc[4] = {0.f, 0.f, 0.f, 0.f};
    const float4* w4 = (const float4*)Wrow;
#pragma unroll 4
    for (int kq = 0; kq < HID / 4; ++kq) {
        float4 wv = w4[kq];
#pragma unroll
        for (int tt = 0; tt < 4; ++tt) {
            float4 hv = ((const float4*)&hlds[tt][0])[kq];
            acc[tt] += wv.x * hv.x + wv.y * hv.y + wv.z * hv.z + wv.w * hv.w;
        }
    }
#pragma unroll
    for (int tt = 0; tt < 4; ++tt) exch[tt][tid] = acc[tt] + bias;
    __syncthreads();

#pragma unroll
    for (int r = 0; r < 2; ++r) {
        const int item = tid + r * 256;
        const int tt = item >> 7;
        const int jj = item & 127;
        const int t  = t0 + tt;
        const float mu = exch[tt][jj];
        const float lv = exch[tt][128 + jj];
        const float e  = eps[(size_t)t * OUT_D + jj];
        const float sd = expf(0.5f * lv);
        const float x  = mu + sd * e;
        const float d  = (x - mu) / sd;
        const float l  = -0.5f * d * d - 0.5f * lv - 0.5f * LOG2PI_F;
        xs[(size_t)t * OUT_D + jj] = x;
        lp[(size_t)t * OUT_D + jj] = l;
    }
}

// ---------------------------------------------------------------------------
extern "C" void kernel_launch(void* const* d_in, const int* in_sizes, int n_in,
                              void* d_out, int out_size, void* d_ws, size_t ws_size,
                              hipStream_t stream)
{
    (void)in_sizes; (void)n_in; (void)out_size; (void)ws_size;

    const float* s0  = (const float*)d_in[0];
    const float* eps = (const float*)d_in[1];
    const float* Wih = (const float*)d_in[2];
    const float* Whh = (const float*)d_in[3];
    const float* bih = (const float*)d_in[4];
    const float* bhh = (const float*)d_in[5];
    const float* Wmu = (const float*)d_in[6];
    const float* bmu = (const float*)d_in[7];
    const float* Wlv = (const float*)d_in[8];
    const float* blv = (const float*)d_in[9];

    float* out = (float*)d_out;
    float* xs = out;                         // [1024][128]
    float* lp = out + TSTEPS * OUT_D;        // [1024][128]
    float* hs = out + 2 * TSTEPS * OUT_D;    // [1024][2048]

    unsigned int* ctr = (unsigned int*)d_ws;
    float* hbuf0 = (float*)((char*)d_ws + 64);
    float* hbuf1 = (float*)((char*)d_ws + 64 + HID * sizeof(float));

    // zero barrier counter + both h buffers (h0 = 0)
    (void)hipMemsetAsync(d_ws, 0, 64 + 2 * HID * sizeof(float), stream);

    hipLaunchKernelGGL(lstm_persist, dim3(NWG), dim3(NTHR), 0, stream,
                       s0, Wih, Whh, bih, bhh, hs, ctr, hbuf0, hbuf1);

    hipLaunchKernelGGL(out_head, dim3(TSTEPS / 4), dim3(256), 0, stream,
                       eps, Wmu, bmu, Wlv, blv, hs, xs, lp);
}